// Round 19
// baseline (1659.885 us; speedup 1.0000x reference)
//
#include <hip/hip_runtime.h>
#include <hip/hip_bf16.h>
#include <math.h>

typedef __hip_bfloat16 bf;
typedef __attribute__((ext_vector_type(8))) short bf8v;   // 8 bf16 = 4 VGPR
typedef __attribute__((ext_vector_type(4))) float f4v;

__device__ __forceinline__ float bf2f(bf v) { return __bfloat162float(v); }
__device__ __forceinline__ bf f2bf(float v) { return __float2bfloat16(v); }
__device__ __forceinline__ unsigned packbf(float a, float b) {
    __hip_bfloat16_raw ra = (__hip_bfloat16_raw)__float2bfloat16(a);
    __hip_bfloat16_raw rb = (__hip_bfloat16_raw)__float2bfloat16(b);
    return (unsigned)ra.x | ((unsigned)rb.x << 16);
}

// ===========================================================================
// Tiled direct 3x3 conv, stride 2 (d2,d3,d4). 16x16 out tile.
// ===========================================================================
template <typename TIN, int STRIDE>
__global__ __launch_bounds__(256)
void conv_tiled(const TIN* __restrict__ inA, const TIN* __restrict__ inB,
                int CiA, int Ci,
                const float* __restrict__ Wt, const float* __restrict__ Bias,
                bf* __restrict__ out,
                int N, int Hi, int Wi, int Co, int Ho, int Wo, int tilesX)
{
    constexpr int TS = 16;
    constexpr int IH = (TS - 1) * STRIDE + 3;
    constexpr int IWP = (IH % 2 == 0) ? IH + 1 : IH;
    constexpr int CHUNK = 8;

    __shared__ TIN  sIn[CHUNK * IH * IWP];
    __shared__ __align__(16) float sW[CHUNK * 144];

    int tile = blockIdx.x;
    int tx0 = (tile % tilesX) * TS, ty0 = (tile / tilesX) * TS;
    int n = blockIdx.y;
    int cog0 = blockIdx.z * 16;
    int t = threadIdx.x;
    int tx = t & 15, ty = t >> 4;
    int CiB = Ci - CiA;

    float acc[16];
    #pragma unroll
    for (int c = 0; c < 16; ++c) acc[c] = Bias[cog0 + c];

    for (int cb = 0; cb < Ci; cb += CHUNK) {
        int cn = (Ci - cb < CHUNK) ? (Ci - cb) : CHUNK;
        for (int e = t; e < cn * IH * IH; e += 256) {
            int ci = e / (IH * IH);
            int rem = e % (IH * IH);
            int py = rem / IH, px = rem % IH;
            int iy = ty0 * STRIDE - 1 + py;
            int ix = tx0 * STRIDE - 1 + px;
            int gci = cb + ci;
            const TIN* src = (gci < CiA)
                ? inA + (size_t)(n * CiA + gci) * Hi * Wi
                : inB + (size_t)(n * CiB + gci - CiA) * Hi * Wi;
            float v = ((unsigned)iy < (unsigned)Hi && (unsigned)ix < (unsigned)Wi)
                      ? (float)src[(size_t)iy * Wi + ix] : 0.f;
            sIn[ci * IH * IWP + py * IWP + px] = (TIN)v;
        }
        for (int e = t; e < cn * 144; e += 256) {
            int ci = e / 144, rem = e % 144;
            int t9 = rem / 16, co = rem % 16;
            sW[ci * 144 + t9 * 16 + co] =
                Wt[(size_t)(cog0 + co) * Ci * 9 + (cb + ci) * 9 + t9];
        }
        __syncthreads();
        for (int ci = 0; ci < cn; ++ci) {
            #pragma unroll
            for (int t9 = 0; t9 < 9; ++t9) {
                int ky = t9 / 3, kx = t9 % 3;
                float v = (float)sIn[ci * IH * IWP + (ty * STRIDE + ky) * IWP
                                     + (tx * STRIDE + kx)];
                const float* wp = &sW[ci * 144 + t9 * 16];
                #pragma unroll
                for (int co = 0; co < 16; ++co)
                    acc[co] = fmaf(v, wp[co], acc[co]);
            }
        }
        __syncthreads();
    }

    int oy = ty0 + ty, ox = tx0 + tx;
    #pragma unroll
    for (int co = 0; co < 16; ++co)
        out[(size_t)(n * Co + cog0 + co) * Ho * Wo + (size_t)oy * Wo + ox]
            = f2bf(fmaxf(acc[co], 0.f));
}

// ===========================================================================
// Stride-1 conv (d1 only, Ci=1). 32x32 tile, 2x2 px/thread.
// ===========================================================================
template <typename TIN>
__global__ __launch_bounds__(256)
void conv32(const TIN* __restrict__ inA, const TIN* __restrict__ inB,
            int CiA, int Ci,
            const float* __restrict__ Wt, const float* __restrict__ Bias,
            bf* __restrict__ out, int N)
{
    constexpr int CHUNK = 4;
    __shared__ float sIn[CHUNK][34][35];
    __shared__ __align__(16) float sW[CHUNK][9][16];

    int tile = blockIdx.x;
    int X0 = (tile & 7) * 32, Y0 = (tile >> 3) * 32;
    int n = blockIdx.y;
    int t = threadIdx.x, tx = t & 15, ty = t >> 4;
    int CiB = Ci - CiA;

    float acc[4][16];
    #pragma unroll
    for (int p = 0; p < 4; ++p)
        #pragma unroll
        for (int c = 0; c < 16; ++c) acc[p][c] = 0.f;

    for (int cb = 0; cb < Ci; cb += CHUNK) {
        int cn = (Ci - cb < CHUNK) ? Ci - cb : CHUNK;
        for (int e = t; e < cn * 1156; e += 256) {
            int ci = e / 1156, rem = e % 1156;
            int py = rem / 34, px = rem % 34;
            int iy = Y0 - 1 + py, ix = X0 - 1 + px;
            int gci = cb + ci;
            const TIN* src = (gci < CiA)
                ? inA + ((size_t)(n * CiA + gci) << 16)
                : inB + ((size_t)(n * CiB + gci - CiA) << 16);
            sIn[ci][py][px] = ((unsigned)iy < 256u && (unsigned)ix < 256u)
                              ? (float)src[(iy << 8) + ix] : 0.f;
        }
        for (int e = t; e < cn * 144; e += 256) {
            int ci = e / 144, rem = e % 144;
            int t9 = rem / 16, co = rem % 16;
            sW[ci][t9][co] = Wt[(size_t)co * Ci * 9 + (cb + ci) * 9 + t9];
        }
        __syncthreads();
        for (int ci = 0; ci < cn; ++ci) {
            float rin[4][4];
            #pragma unroll
            for (int a = 0; a < 4; ++a)
                #pragma unroll
                for (int b = 0; b < 4; ++b)
                    rin[a][b] = sIn[ci][2 * ty + a][2 * tx + b];
            #pragma unroll
            for (int t9 = 0; t9 < 9; ++t9) {
                const int ky = t9 / 3, kx = t9 % 3;
                float w[16];
                #pragma unroll
                for (int q = 0; q < 4; ++q)
                    *(float4*)&w[q * 4] = *(const float4*)&sW[ci][t9][q * 4];
                #pragma unroll
                for (int ry = 0; ry < 2; ++ry)
                    #pragma unroll
                    for (int rx = 0; rx < 2; ++rx) {
                        float v = rin[ry + ky][rx + kx];
                        #pragma unroll
                        for (int co = 0; co < 16; ++co)
                            acc[ry * 2 + rx][co] = fmaf(v, w[co], acc[ry * 2 + rx][co]);
                    }
            }
        }
        __syncthreads();
    }

    #pragma unroll
    for (int co = 0; co < 16; ++co) {
        float bs = Bias[co];
        bf* dst = out + ((size_t)(n * 16 + co) << 16);
        #pragma unroll
        for (int ry = 0; ry < 2; ++ry) {
            unsigned pk = packbf(fmaxf(acc[ry * 2 + 0][co] + bs, 0.f),
                                 fmaxf(acc[ry * 2 + 1][co] + bs, 0.f));
            *(unsigned*)(dst + ((Y0 + 2 * ty + ry) << 8) + X0 + 2 * tx) = pk;
        }
    }
}

// ===========================================================================
// MFMA implicit-GEMM stride-1 conv: Co=16, Ci template (16 or 32), 256x256.
// (verified correct in round 13)
// ===========================================================================
template <int CI, int KPAD>
__global__ __launch_bounds__(256)
void conv_mfma(const bf* __restrict__ inA, const bf* __restrict__ inB,
               int CiA,
               const float* __restrict__ Wt, const float* __restrict__ Bias,
               bf* __restrict__ out, int N)
{
    constexpr int K = CI * 9;
    constexpr int NM = KPAD / 32;
    __shared__ bf sIn[CI][18][19];
    __shared__ __align__(16) bf sWt[16][KPAD];

    int tile = blockIdx.x;
    int X0 = (tile & 15) * 16, Y0 = (tile >> 4) * 16;
    int n = blockIdx.y;
    int t = threadIdx.x;
    int lane = t & 63, wave = t >> 6;
    int q = lane >> 4, mcol = lane & 15;
    int CiB = CI - CiA;

    for (int e = t; e < 16 * KPAD; e += 256) {
        int co = e / KPAD, k = e % KPAD;
        sWt[co][k] = (k < K) ? f2bf(Wt[(size_t)co * K + k]) : f2bf(0.f);
    }
    for (int e = t; e < CI * 324; e += 256) {
        int ci = e / 324, rem = e % 324;
        int py = rem / 18, px = rem % 18;
        int iy = Y0 - 1 + py, ix = X0 - 1 + px;
        const bf* src = (ci < CiA)
            ? inA + ((size_t)(n * CiA + ci) << 16)
            : inB + ((size_t)(n * CiB + ci - CiA) << 16);
        bf v;
        if ((unsigned)iy < 256u && (unsigned)ix < 256u) v = src[(iy << 8) + ix];
        else v = f2bf(0.f);
        sIn[ci][py][px] = v;
    }
    __syncthreads();

    bf8v wfrag[NM];
    #pragma unroll
    for (int s = 0; s < NM; ++s)
        wfrag[s] = *(const bf8v*)&sWt[mcol][s * 32 + q * 8];

    f4v acc[4];
    #pragma unroll
    for (int g = 0; g < 4; ++g) acc[g] = (f4v){0.f, 0.f, 0.f, 0.f};

    const bf* flat = (const bf*)sIn;
    int prow0 = wave * 4;
    #pragma unroll
    for (int s = 0; s < NM; ++s) {
        int toff[8];
        #pragma unroll
        for (int j = 0; j < 8; ++j) {
            int k = s * 32 + q * 8 + j;
            int ci = (k * 57) >> 9;
            int rem = k - ci * 9;
            int ky = (rem * 11) >> 5;
            int kx = rem - ky * 3;
            toff[j] = (k < K) ? (ci * 342 + ky * 19 + kx) : 0;
        }
        #pragma unroll
        for (int g = 0; g < 4; ++g) {
            int base = (prow0 + g) * 19 + mcol;
            unsigned short v[8];
            #pragma unroll
            for (int j = 0; j < 8; ++j) {
                int k = s * 32 + q * 8 + j;
                bf raw = flat[toff[j] + base];
                __hip_bfloat16_raw r = (__hip_bfloat16_raw)raw;
                v[j] = (k < K) ? r.x : (unsigned short)0;
            }
            bf8v afrag;
            #pragma unroll
            for (int j = 0; j < 8; ++j) afrag[j] = (short)v[j];
            acc[g] = __builtin_amdgcn_mfma_f32_16x16x32_bf16(afrag, wfrag[s], acc[g], 0, 0, 0);
        }
    }

    float bs = Bias[mcol];
    bf* dst = out + ((size_t)(n * 16 + mcol) << 16);
    #pragma unroll
    for (int g = 0; g < 4; ++g) {
        int oy = Y0 + prow0 + g, ox = X0 + q * 4;
        uint2 pk;
        pk.x = packbf(fmaxf(acc[g][0] + bs, 0.f), fmaxf(acc[g][1] + bs, 0.f));
        pk.y = packbf(fmaxf(acc[g][2] + bs, 0.f), fmaxf(acc[g][3] + bs, 0.f));
        *(uint2*)(dst + (oy << 8) + ox) = pk;
    }
}

// ===========================================================================
// MFMA phase-decomposed transposed conv (k=3,s=2,p=1,op=1): u1,u2,u3.
// Round-15-verified structure, chunk halved 32->16 ci to cut LDS 30.2->14.9KB
// (occupancy 2->4 blocks/CU under the ~64KB effective LDS window).
// Phase K: 16(pad 32)/32/32/64, sWt bases 0/32/64/96 (all 16B-aligned).
// KV guards toff for the zero-padded half of phase 0 (weights there = 0).
// ===========================================================================
#define CVT_PHASE(PH, KBASE, NCHAIN, L2NT, L2NTX, KV)                          \
    _Pragma("unroll")                                                          \
    for (int s = 0; s < NCHAIN; ++s) {                                         \
        bf8v wf = *(const bf8v*)&sWt[mcol][(KBASE) + s * 32 + q * 8];          \
        int toff[8];                                                           \
        _Pragma("unroll")                                                      \
        for (int j = 0; j < 8; ++j) {                                          \
            int k = s * 32 + q * 8 + j;                                        \
            int cic = k >> (L2NT);                                             \
            int tap = k & ((1 << (L2NT)) - 1);                                 \
            int ay = tap >> (L2NTX);                                           \
            int ax = tap & ((1 << (L2NTX)) - 1);                               \
            toff[j] = (k < (KV)) ? (cic * 306 + ay * 18 + ax) : 0;             \
        }                                                                      \
        _Pragma("unroll")                                                      \
        for (int g = 0; g < 4; ++g) {                                          \
            int base = (prow0 + g) * 18 + mcol;                                \
            bf8v af;                                                           \
            _Pragma("unroll")                                                  \
            for (int j = 0; j < 8; ++j) {                                      \
                __hip_bfloat16_raw r = (__hip_bfloat16_raw)flat[toff[j] + base];\
                af[j] = (short)r.x;                                            \
            }                                                                  \
            acc[PH][g] = __builtin_amdgcn_mfma_f32_16x16x32_bf16(af, wf,       \
                                                      acc[PH][g], 0, 0, 0);    \
        }                                                                      \
    }

template <int CITOT, int CIA>
__global__ __launch_bounds__(256)
void convt_mfma(const bf* __restrict__ inA, const bf* __restrict__ inB,
                const float* __restrict__ Wt, const float* __restrict__ Bias,
                bf* __restrict__ out,
                int N, int Hi, int Wi, int Cotot, int Ho, int Wo, int tilesX)
{
    constexpr int NCH = CITOT / 16;
    __shared__ bf sIn[16][17][18];                // 306 elems per ci (9.8KB)
    __shared__ __align__(16) bf sWt[16][160];     // phase bases 0,32,64,96 (5.1KB)

    int tile = blockIdx.x;
    int J0 = (tile % tilesX) * 16, I0 = (tile / tilesX) * 16;
    int n = blockIdx.y;
    int cog0 = blockIdx.z * 16;
    int t = threadIdx.x;
    int lane = t & 63, wave = t >> 6;
    int q = lane >> 4, mcol = lane & 15;
    int prow0 = wave * 4;

    f4v acc[4][4];
    #pragma unroll
    for (int p = 0; p < 4; ++p)
        #pragma unroll
        for (int g = 0; g < 4; ++g) acc[p][g] = (f4v){0.f, 0.f, 0.f, 0.f};

    const bf* flat = (const bf*)sIn;

    for (int cb = 0; cb < NCH; ++cb) {
        if (cb) __syncthreads();                  // drain reads before restage
        // stage input chunk: 16 ch x 17x17 (row stride 18), zero-padded
        for (int e = t; e < 16 * 306; e += 256) {
            int ci = e / 306, rem = e % 306;
            int py = rem / 18, px = rem % 18;
            int iy = I0 + py, ix = J0 + px;
            int gci = cb * 16 + ci;
            const bf* src = (gci < CIA)
                ? inA + (size_t)(n * CIA + gci) * Hi * Wi
                : inB + (size_t)(n * (CITOT - CIA) + gci - CIA) * Hi * Wi;
            sIn[ci][py][px] = (py < 17 && iy < Hi && px < 17 && ix < Wi)
                              ? src[(size_t)iy * Wi + ix] : f2bf(0.f);
        }
        // stage weights: inverse map per k-slot (16 co x 160 slots)
        for (int e = t; e < 16 * 160; e += 256) {
            int co = e / 160, k = e % 160;
            bf v = f2bf(0.f);
            int cic = 0, t9 = -1;
            if (k < 32)       { if (k < 16) { cic = k; t9 = 4; } }
            else if (k < 64)  { int kk = k - 32; cic = kk >> 1; t9 = 3 + 2 * (kk & 1); }
            else if (k < 96)  { int kk = k - 64; cic = kk >> 1; t9 = 1 + 6 * (kk & 1); }
            else              { int kk = k - 96; cic = kk >> 2;
                                t9 = 6 * ((kk >> 1) & 1) + 2 * (kk & 1); }
            if (t9 >= 0)
                v = f2bf(Wt[(size_t)(cog0 + co) * CITOT * 9
                            + (size_t)(cb * 16 + cic) * 9 + t9]);
            sWt[co][k] = v;
        }
        __syncthreads();

        //        PH  KBASE NCH L2NT L2NTX KV
        CVT_PHASE(0,   0, 1, 0, 0, 16)    // (ry0,rx0) tap(1,1), K=16 pad 32
        CVT_PHASE(1,  32, 1, 1, 1, 64)    // (ry0,rx1) kx in {0,2}, K=32
        CVT_PHASE(2,  64, 1, 1, 0, 64)    // (ry1,rx0) ky in {0,2}, K=32
        CVT_PHASE(3,  96, 2, 2, 1, 64)    // (ry1,rx1) 4 taps, K=64
    }

    float bs = Bias[cog0 + mcol];
    bf* dst = out + (size_t)(n * Cotot + cog0 + mcol) * Ho * Wo;
    #pragma unroll
    for (int ph = 0; ph < 4; ++ph) {
        const int ry = ph >> 1, rx = ph & 1;
        #pragma unroll
        for (int g = 0; g < 4; ++g) {
            int oy = 2 * (I0 + prow0 + g) + ry;
            #pragma unroll
            for (int jj = 0; jj < 4; ++jj) {
                int ox = 2 * (J0 + q * 4 + jj) + rx;
                dst[(size_t)oy * Wo + ox] = f2bf(fmaxf(acc[ph][g][jj] + bs, 0.f));
            }
        }
    }
}

// ===========================================================================
// Pairwise Gram partials over 256-feature chunks. Deterministic.
// ===========================================================================
#define SCH 256
__global__ void sim_partial(const bf* __restrict__ f, float* __restrict__ part, int KTOT)
{
    __shared__ float tile[32][SCH + 1];
    int c = blockIdx.x;
    int t = threadIdx.x;
    int k0 = c * SCH;
    for (int r = 0; r < 32; ++r)
        tile[r][t] = bf2f(f[(size_t)r * KTOT + k0 + t]);
    __syncthreads();
    int i = t >> 3;
    int j0 = (t & 7) * 4;
    float a0 = 0.f, a1 = 0.f, a2 = 0.f, a3 = 0.f;
    for (int k = 0; k < SCH; ++k) {
        float fi = tile[i][k];
        a0 = fmaf(fi, tile[j0 + 0][k], a0);
        a1 = fmaf(fi, tile[j0 + 1][k], a1);
        a2 = fmaf(fi, tile[j0 + 2][k], a2);
        a3 = fmaf(fi, tile[j0 + 3][k], a3);
    }
    float* dst = part + (size_t)c * 1024 + i * 32 + j0;
    dst[0] = a0; dst[1] = a1; dst[2] = a2; dst[3] = a3;
}

__global__ __launch_bounds__(256)
void sim_reduce(const float* __restrict__ part, float* __restrict__ sim, int nchunks)
{
    __shared__ float red[256];
    int pair = blockIdx.x;
    int t = threadIdx.x;
    float s = 0.f;
    for (int k = t; k < nchunks; k += 256)
        s += part[(size_t)k * 1024 + pair];
    red[t] = s;
    __syncthreads();
    #pragma unroll
    for (int off = 128; off > 0; off >>= 1) {
        if (t < off) red[t] += red[t + off];
        __syncthreads();
    }
    if (t == 0) sim[pair] = red[0];
}

// ===========================================================================
// Cosine sim + group mask + top-3 (strict >, lowest index wins ties).
// ===========================================================================
__global__ void topk_kernel(const float* __restrict__ sim, const int* __restrict__ prange,
                            int* __restrict__ idx, int N)
{
    int i = threadIdx.x;
    if (i >= N) return;
    float nm_i = fmaxf(sqrtf(sim[i * N + i]), 1e-8f);
    int p0 = prange[0], p1 = prange[1];
    int gi = (i >= p0) + (i >= p1);
    float vals[32];
    for (int j = 0; j < N; ++j) {
        int gj = (j >= p0) + (j >= p1);
        if (j == i || gj != gi) { vals[j] = -1e30f; continue; }
        float nm_j = fmaxf(sqrtf(sim[j * N + j]), 1e-8f);
        vals[j] = sim[i * N + j] / (nm_i * nm_j);
    }
    for (int k = 0; k < 3; ++k) {
        float best = -2e30f; int bj = 0;
        for (int j = 0; j < N; ++j)
            if (vals[j] > best) { best = vals[j]; bj = j; }
        idx[i * 3 + k] = bj;
        vals[bj] = -1e30f;
    }
}

// ===========================================================================
// Gather-mean: agg[n] = (ga[i0] + ga[i1] + ga[i2]) / 3.
// ===========================================================================
__global__ __launch_bounds__(256)
void gather_mean(const bf* __restrict__ ga, const int* __restrict__ idx,
                 bf* __restrict__ agg)
{
    int n = blockIdx.y;
    int v = blockIdx.x * 256 + threadIdx.x;
    int i0 = idx[n * 3 + 0], i1 = idx[n * 3 + 1], i2 = idx[n * 3 + 2];
    const size_t stride = (size_t)16 << 16;
    const uint4* p0 = (const uint4*)(ga + stride * i0) + v;
    const uint4* p1 = (const uint4*)(ga + stride * i1) + v;
    const uint4* p2 = (const uint4*)(ga + stride * i2) + v;
    uint4 a = *p0, b = *p1, c = *p2;
    uint4 r;
    unsigned* ap = (unsigned*)&a; unsigned* bp = (unsigned*)&b;
    unsigned* cp = (unsigned*)&c; unsigned* rp = (unsigned*)&r;
    #pragma unroll
    for (int w = 0; w < 4; ++w) {
        float fa0 = __bfloat162float((__hip_bfloat16_raw){(unsigned short)(ap[w] & 0xffff)});
        float fb0 = __bfloat162float((__hip_bfloat16_raw){(unsigned short)(bp[w] & 0xffff)});
        float fc0 = __bfloat162float((__hip_bfloat16_raw){(unsigned short)(cp[w] & 0xffff)});
        float fa1 = __bfloat162float((__hip_bfloat16_raw){(unsigned short)(ap[w] >> 16)});
        float fb1 = __bfloat162float((__hip_bfloat16_raw){(unsigned short)(bp[w] >> 16)});
        float fc1 = __bfloat162float((__hip_bfloat16_raw){(unsigned short)(cp[w] >> 16)});
        rp[w] = packbf((fa0 + fb0 + fc0) * (1.f / 3.f),
                       (fa1 + fb1 + fc1) * (1.f / 3.f));
    }
    *((uint4*)(agg + stride * n) + v) = r;
}

// ===========================================================================
// Light head: gnn (bf16) + d1 recompute + dense 32->2 + softmax.
// ===========================================================================
__global__ __launch_bounds__(256)
void head_tiled(const float* __restrict__ cts, const bf* __restrict__ gnn,
                const float* __restrict__ w_d1, const float* __restrict__ b_d1,
                const float* __restrict__ w_de, const float* __restrict__ b_de,
                float* __restrict__ out, int N)
{
    __shared__ float sCts[18][19];
    __shared__ float sWd1[144];
    __shared__ float sB1[16];
    __shared__ float sDe[64];

    int tile = blockIdx.x;
    int X0 = (tile & 15) * 16, Y0 = (tile >> 4) * 16;
    int n = blockIdx.y;
    int t = threadIdx.x, tx = t & 15, ty = t >> 4;

    for (int e = t; e < 18 * 18; e += 256) {
        int py = e / 18, px = e % 18;
        int iy = Y0 - 1 + py, ix = X0 - 1 + px;
        sCts[py][px] = ((unsigned)iy < 256u && (unsigned)ix < 256u)
                       ? cts[((size_t)n << 16) + (iy << 8) + ix] : 0.f;
    }
    if (t < 144) sWd1[t] = w_d1[t];
    else if (t < 160) sB1[t - 144] = b_d1[t - 144];
    else if (t >= 192 && t < 256) sDe[t - 192] = w_de[t - 192];
    __syncthreads();

    int pix = ((Y0 + ty) << 8) + X0 + tx;
    float l0 = b_de[0], l1 = b_de[1];

    #pragma unroll
    for (int c = 0; c < 16; ++c) {
        float v = bf2f(gnn[((size_t)(n * 16 + c) << 16) + pix]);
        l0 = fmaf(v, sDe[c * 2 + 0], l0);
        l1 = fmaf(v, sDe[c * 2 + 1], l1);
    }

    float ct[3][3];
    #pragma unroll
    for (int a = 0; a < 3; ++a)
        #pragma unroll
        for (int b = 0; b < 3; ++b)
            ct[a][b] = sCts[ty + a][tx + b];
    #pragma unroll
    for (int c = 0; c < 16; ++c) {
        float a1 = sB1[c];
        #pragma unroll
        for (int t9 = 0; t9 < 9; ++t9)
            a1 = fmaf(ct[t9 / 3][t9 % 3], sWd1[c * 9 + t9], a1);
        float v = fmaxf(a1, 0.f);
        l0 = fmaf(v, sDe[(16 + c) * 2 + 0], l0);
        l1 = fmaf(v, sDe[(16 + c) * 2 + 1], l1);
    }

    float m = fmaxf(l0, l1);
    float e0 = expf(l0 - m), e1 = expf(l1 - m);
    float inv = 1.f / (e0 + e1);
    size_t base = ((size_t)n * 2) << 16;
    out[base + pix] = e0 * inv;
    out[base + 65536 + pix] = e1 * inv;
}

// ===========================================================================

extern "C" void kernel_launch(void* const* d_in, const int* in_sizes, int n_in,
                              void* d_out, int out_size, void* d_ws, size_t ws_size,
                              hipStream_t stream)
{
    const float* cts  = (const float*)d_in[0];
    const int*   prng = (const int*)d_in[1];
    const float* w_d1 = (const float*)d_in[2];  const float* b_d1 = (const float*)d_in[3];
    const float* w_d2 = (const float*)d_in[4];  const float* b_d2 = (const float*)d_in[5];
    const float* w_d3 = (const float*)d_in[6];  const float* b_d3 = (const float*)d_in[7];
    const float* w_d4 = (const float*)d_in[8];  const float* b_d4 = (const float*)d_in[9];
    const float* w_u1 = (const float*)d_in[10]; const float* b_u1 = (const float*)d_in[11];
    const float* w_u2 = (const float*)d_in[12]; const float* b_u2 = (const float*)d_in[13];
    const float* w_u3 = (const float*)d_in[14]; const float* b_u3 = (const float*)d_in[15];
    const float* w_ga = (const float*)d_in[16]; const float* b_ga = (const float*)d_in[17];
    const float* w_gu = (const float*)d_in[18]; const float* b_gu = (const float*)d_in[19];
    const float* w_de = (const float*)d_in[20]; const float* b_de = (const float*)d_in[21];

    const int H = 256, Wd = 256;
    const int N = in_sizes[0] / (H * Wd);   // 32

    // ---- workspace layout (192 MiB total), lifetime reuse ----
    char* wsb = (char*)d_ws;
    bf* u3 = (bf*)(wsb);
    bf* R1 = (bf*)(wsb + 67108864);

    bf* d1 = R1;
    bf* d2 = (bf*)(wsb + 134217728);
    bf* d3 = (bf*)(wsb + 134217728 + 33554432);
    bf* d4 = (bf*)(wsb + 134217728 + 50331648);
    bf* u1 = R1;
    bf* u2 = (bf*)(wsb + 67108864 + 16777216);
    bf* ga = R1;
    bf* gnn = R1;
    bf* agg = (bf*)(wsb + 134217728);
    float* simp = (float*)(wsb + 134217728);
    float* sim  = (float*)(wsb + 134217728 + 16777216);
    int*   idx  = (int*)d_out + (out_size - 96);

    const int KTOT = 16 * H * Wd;
    const int NCH  = KTOT / SCH;

    // encoder
    conv32<float><<<dim3(64, N), 256, 0, stream>>>(cts, cts, 1, 1, w_d1, b_d1, d1, N);
    conv_tiled<bf, 2><<<dim3(64, N, 2), 256, 0, stream>>>(
        d1, (const bf*)nullptr, 16, 16, w_d2, b_d2, d2, N, 256, 256, 32, 128, 128, 8);
    conv_tiled<bf, 2><<<dim3(16, N, 4), 256, 0, stream>>>(
        d2, (const bf*)nullptr, 32, 32, w_d3, b_d3, d3, N, 128, 128, 64, 64, 64, 4);
    conv_tiled<bf, 2><<<dim3(4, N, 8), 256, 0, stream>>>(
        d3, (const bf*)nullptr, 64, 64, w_d4, b_d4, d4, N, 64, 64, 128, 32, 32, 2);
    // decoder (all transposed convs via MFMA)
    convt_mfma<128, 128><<<dim3(4, N, 4), 256, 0, stream>>>(
        d4, d4, w_u1, b_u1, u1, N, 32, 32, 64, 64, 64, 2);
    convt_mfma<128, 64><<<dim3(16, N, 2), 256, 0, stream>>>(
        u1, d3, w_u2, b_u2, u2, N, 64, 64, 32, 128, 128, 4);
    convt_mfma<64, 32><<<dim3(64, N, 1), 256, 0, stream>>>(
        u2, d2, w_u3, b_u3, u3, N, 128, 128, 16, 256, 256, 8);
    // cosine similarity + top-3
    sim_partial<<<NCH, 256, 0, stream>>>(u3, simp, KTOT);
    sim_reduce<<<dim3(N * N), 256, 0, stream>>>(simp, sim, NCH);
    topk_kernel<<<1, 64, 0, stream>>>(sim, prng, idx, N);
    // per-slice gnn-neighbor conv (MFMA), then gather-mean
    conv_mfma<16, 160><<<dim3(256, N), 256, 0, stream>>>(
        u3, u3, 16, w_ga, b_ga, ga, N);
    gather_mean<<<dim3(512, N), 256, 0, stream>>>(ga, idx, agg);
    // gnn conv (MFMA, 32ch from u3|agg) then light head
    conv_mfma<32, 288><<<dim3(256, N), 256, 0, stream>>>(
        u3, agg, 16, w_gu, b_gu, gnn, N);
    head_tiled<<<dim3(256, N), 256, 0, stream>>>(
        cts, gnn, w_d1, b_d1, w_de, b_de, (float*)d_out, N);
}

// Round 20
// 1589.195 us; speedup vs baseline: 1.0445x; 1.0445x over previous
//
#include <hip/hip_runtime.h>
#include <hip/hip_bf16.h>
#include <math.h>

typedef __hip_bfloat16 bf;
typedef __attribute__((ext_vector_type(8))) short bf8v;   // 8 bf16 = 4 VGPR
typedef __attribute__((ext_vector_type(4))) float f4v;

__device__ __forceinline__ float bf2f(bf v) { return __bfloat162float(v); }
__device__ __forceinline__ bf f2bf(float v) { return __float2bfloat16(v); }
__device__ __forceinline__ unsigned packbf(float a, float b) {
    __hip_bfloat16_raw ra = (__hip_bfloat16_raw)__float2bfloat16(a);
    __hip_bfloat16_raw rb = (__hip_bfloat16_raw)__float2bfloat16(b);
    return (unsigned)ra.x | ((unsigned)rb.x << 16);
}

// ===========================================================================
// Tiled direct 3x3 conv, stride 2 (d2,d3,d4). 16x16 out tile.
// ===========================================================================
template <typename TIN, int STRIDE>
__global__ __launch_bounds__(256)
void conv_tiled(const TIN* __restrict__ inA, const TIN* __restrict__ inB,
                int CiA, int Ci,
                const float* __restrict__ Wt, const float* __restrict__ Bias,
                bf* __restrict__ out,
                int N, int Hi, int Wi, int Co, int Ho, int Wo, int tilesX)
{
    constexpr int TS = 16;
    constexpr int IH = (TS - 1) * STRIDE + 3;
    constexpr int IWP = (IH % 2 == 0) ? IH + 1 : IH;
    constexpr int CHUNK = 8;

    __shared__ TIN  sIn[CHUNK * IH * IWP];
    __shared__ __align__(16) float sW[CHUNK * 144];

    int tile = blockIdx.x;
    int tx0 = (tile % tilesX) * TS, ty0 = (tile / tilesX) * TS;
    int n = blockIdx.y;
    int cog0 = blockIdx.z * 16;
    int t = threadIdx.x;
    int tx = t & 15, ty = t >> 4;
    int CiB = Ci - CiA;

    float acc[16];
    #pragma unroll
    for (int c = 0; c < 16; ++c) acc[c] = Bias[cog0 + c];

    for (int cb = 0; cb < Ci; cb += CHUNK) {
        int cn = (Ci - cb < CHUNK) ? (Ci - cb) : CHUNK;
        for (int e = t; e < cn * IH * IH; e += 256) {
            int ci = e / (IH * IH);
            int rem = e % (IH * IH);
            int py = rem / IH, px = rem % IH;
            int iy = ty0 * STRIDE - 1 + py;
            int ix = tx0 * STRIDE - 1 + px;
            int gci = cb + ci;
            const TIN* src = (gci < CiA)
                ? inA + (size_t)(n * CiA + gci) * Hi * Wi
                : inB + (size_t)(n * CiB + gci - CiA) * Hi * Wi;
            float v = ((unsigned)iy < (unsigned)Hi && (unsigned)ix < (unsigned)Wi)
                      ? (float)src[(size_t)iy * Wi + ix] : 0.f;
            sIn[ci * IH * IWP + py * IWP + px] = (TIN)v;
        }
        for (int e = t; e < cn * 144; e += 256) {
            int ci = e / 144, rem = e % 144;
            int t9 = rem / 16, co = rem % 16;
            sW[ci * 144 + t9 * 16 + co] =
                Wt[(size_t)(cog0 + co) * Ci * 9 + (cb + ci) * 9 + t9];
        }
        __syncthreads();
        for (int ci = 0; ci < cn; ++ci) {
            #pragma unroll
            for (int t9 = 0; t9 < 9; ++t9) {
                int ky = t9 / 3, kx = t9 % 3;
                float v = (float)sIn[ci * IH * IWP + (ty * STRIDE + ky) * IWP
                                     + (tx * STRIDE + kx)];
                const float* wp = &sW[ci * 144 + t9 * 16];
                #pragma unroll
                for (int co = 0; co < 16; ++co)
                    acc[co] = fmaf(v, wp[co], acc[co]);
            }
        }
        __syncthreads();
    }

    int oy = ty0 + ty, ox = tx0 + tx;
    #pragma unroll
    for (int co = 0; co < 16; ++co)
        out[(size_t)(n * Co + cog0 + co) * Ho * Wo + (size_t)oy * Wo + ox]
            = f2bf(fmaxf(acc[co], 0.f));
}

// ===========================================================================
// Stride-1 conv (d1 only, Ci=1). 32x32 tile, 2x2 px/thread.
// ===========================================================================
template <typename TIN>
__global__ __launch_bounds__(256)
void conv32(const TIN* __restrict__ inA, const TIN* __restrict__ inB,
            int CiA, int Ci,
            const float* __restrict__ Wt, const float* __restrict__ Bias,
            bf* __restrict__ out, int N)
{
    constexpr int CHUNK = 4;
    __shared__ float sIn[CHUNK][34][35];
    __shared__ __align__(16) float sW[CHUNK][9][16];

    int tile = blockIdx.x;
    int X0 = (tile & 7) * 32, Y0 = (tile >> 3) * 32;
    int n = blockIdx.y;
    int t = threadIdx.x, tx = t & 15, ty = t >> 4;
    int CiB = Ci - CiA;

    float acc[4][16];
    #pragma unroll
    for (int p = 0; p < 4; ++p)
        #pragma unroll
        for (int c = 0; c < 16; ++c) acc[p][c] = 0.f;

    for (int cb = 0; cb < Ci; cb += CHUNK) {
        int cn = (Ci - cb < CHUNK) ? Ci - cb : CHUNK;
        for (int e = t; e < cn * 1156; e += 256) {
            int ci = e / 1156, rem = e % 1156;
            int py = rem / 34, px = rem % 34;
            int iy = Y0 - 1 + py, ix = X0 - 1 + px;
            int gci = cb + ci;
            const TIN* src = (gci < CiA)
                ? inA + ((size_t)(n * CiA + gci) << 16)
                : inB + ((size_t)(n * CiB + gci - CiA) << 16);
            sIn[ci][py][px] = ((unsigned)iy < 256u && (unsigned)ix < 256u)
                              ? (float)src[(iy << 8) + ix] : 0.f;
        }
        for (int e = t; e < cn * 144; e += 256) {
            int ci = e / 144, rem = e % 144;
            int t9 = rem / 16, co = rem % 16;
            sW[ci][t9][co] = Wt[(size_t)co * Ci * 9 + (cb + ci) * 9 + t9];
        }
        __syncthreads();
        for (int ci = 0; ci < cn; ++ci) {
            float rin[4][4];
            #pragma unroll
            for (int a = 0; a < 4; ++a)
                #pragma unroll
                for (int b = 0; b < 4; ++b)
                    rin[a][b] = sIn[ci][2 * ty + a][2 * tx + b];
            #pragma unroll
            for (int t9 = 0; t9 < 9; ++t9) {
                const int ky = t9 / 3, kx = t9 % 3;
                float w[16];
                #pragma unroll
                for (int q = 0; q < 4; ++q)
                    *(float4*)&w[q * 4] = *(const float4*)&sW[ci][t9][q * 4];
                #pragma unroll
                for (int ry = 0; ry < 2; ++ry)
                    #pragma unroll
                    for (int rx = 0; rx < 2; ++rx) {
                        float v = rin[ry + ky][rx + kx];
                        #pragma unroll
                        for (int co = 0; co < 16; ++co)
                            acc[ry * 2 + rx][co] = fmaf(v, w[co], acc[ry * 2 + rx][co]);
                    }
            }
        }
        __syncthreads();
    }

    #pragma unroll
    for (int co = 0; co < 16; ++co) {
        float bs = Bias[co];
        bf* dst = out + ((size_t)(n * 16 + co) << 16);
        #pragma unroll
        for (int ry = 0; ry < 2; ++ry) {
            unsigned pk = packbf(fmaxf(acc[ry * 2 + 0][co] + bs, 0.f),
                                 fmaxf(acc[ry * 2 + 1][co] + bs, 0.f));
            *(unsigned*)(dst + ((Y0 + 2 * ty + ry) << 8) + X0 + 2 * tx) = pk;
        }
    }
}

// ===========================================================================
// MFMA implicit-GEMM stride-1 conv: Co=16, Ci template (16 or 32), 256x256.
// (verified correct in round 13)
// ===========================================================================
template <int CI, int KPAD>
__global__ __launch_bounds__(256)
void conv_mfma(const bf* __restrict__ inA, const bf* __restrict__ inB,
               int CiA,
               const float* __restrict__ Wt, const float* __restrict__ Bias,
               bf* __restrict__ out, int N)
{
    constexpr int K = CI * 9;
    constexpr int NM = KPAD / 32;
    __shared__ bf sIn[CI][18][19];
    __shared__ __align__(16) bf sWt[16][KPAD];

    int tile = blockIdx.x;
    int X0 = (tile & 15) * 16, Y0 = (tile >> 4) * 16;
    int n = blockIdx.y;
    int t = threadIdx.x;
    int lane = t & 63, wave = t >> 6;
    int q = lane >> 4, mcol = lane & 15;
    int CiB = CI - CiA;

    for (int e = t; e < 16 * KPAD; e += 256) {
        int co = e / KPAD, k = e % KPAD;
        sWt[co][k] = (k < K) ? f2bf(Wt[(size_t)co * K + k]) : f2bf(0.f);
    }
    for (int e = t; e < CI * 324; e += 256) {
        int ci = e / 324, rem = e % 324;
        int py = rem / 18, px = rem % 18;
        int iy = Y0 - 1 + py, ix = X0 - 1 + px;
        const bf* src = (ci < CiA)
            ? inA + ((size_t)(n * CiA + ci) << 16)
            : inB + ((size_t)(n * CiB + ci - CiA) << 16);
        bf v;
        if ((unsigned)iy < 256u && (unsigned)ix < 256u) v = src[(iy << 8) + ix];
        else v = f2bf(0.f);
        sIn[ci][py][px] = v;
    }
    __syncthreads();

    bf8v wfrag[NM];
    #pragma unroll
    for (int s = 0; s < NM; ++s)
        wfrag[s] = *(const bf8v*)&sWt[mcol][s * 32 + q * 8];

    f4v acc[4];
    #pragma unroll
    for (int g = 0; g < 4; ++g) acc[g] = (f4v){0.f, 0.f, 0.f, 0.f};

    const bf* flat = (const bf*)sIn;
    int prow0 = wave * 4;
    #pragma unroll
    for (int s = 0; s < NM; ++s) {
        int toff[8];
        #pragma unroll
        for (int j = 0; j < 8; ++j) {
            int k = s * 32 + q * 8 + j;
            int ci = (k * 57) >> 9;
            int rem = k - ci * 9;
            int ky = (rem * 11) >> 5;
            int kx = rem - ky * 3;
            toff[j] = (k < K) ? (ci * 342 + ky * 19 + kx) : 0;
        }
        #pragma unroll
        for (int g = 0; g < 4; ++g) {
            int base = (prow0 + g) * 19 + mcol;
            unsigned short v[8];
            #pragma unroll
            for (int j = 0; j < 8; ++j) {
                int k = s * 32 + q * 8 + j;
                bf raw = flat[toff[j] + base];
                __hip_bfloat16_raw r = (__hip_bfloat16_raw)raw;
                v[j] = (k < K) ? r.x : (unsigned short)0;
            }
            bf8v afrag;
            #pragma unroll
            for (int j = 0; j < 8; ++j) afrag[j] = (short)v[j];
            acc[g] = __builtin_amdgcn_mfma_f32_16x16x32_bf16(afrag, wfrag[s], acc[g], 0, 0, 0);
        }
    }

    float bs = Bias[mcol];
    bf* dst = out + ((size_t)(n * 16 + mcol) << 16);
    #pragma unroll
    for (int g = 0; g < 4; ++g) {
        int oy = Y0 + prow0 + g, ox = X0 + q * 4;
        uint2 pk;
        pk.x = packbf(fmaxf(acc[g][0] + bs, 0.f), fmaxf(acc[g][1] + bs, 0.f));
        pk.y = packbf(fmaxf(acc[g][2] + bs, 0.f), fmaxf(acc[g][3] + bs, 0.f));
        *(uint2*)(dst + (oy << 8) + ox) = pk;
    }
}

// ===========================================================================
// MFMA phase-decomposed transposed conv (k=3,s=2,p=1,op=1): u1,u2,u3.
// (verified correct in round 15; 32-ci chunk form)
// ===========================================================================
#define CVT_PHASE(PH, KBASE, NCHAIN, L2NT, L2NTX)                              \
    _Pragma("unroll")                                                          \
    for (int s = 0; s < NCHAIN; ++s) {                                         \
        bf8v wf = *(const bf8v*)&sWt[mcol][(KBASE) + s * 32 + q * 8];          \
        int toff[8];                                                           \
        _Pragma("unroll")                                                      \
        for (int j = 0; j < 8; ++j) {                                          \
            int k = s * 32 + q * 8 + j;                                        \
            int cic = k >> (L2NT);                                             \
            int tap = k & ((1 << (L2NT)) - 1);                                 \
            int ay = tap >> (L2NTX);                                           \
            int ax = tap & ((1 << (L2NTX)) - 1);                               \
            toff[j] = cic * 306 + ay * 18 + ax;                                \
        }                                                                      \
        _Pragma("unroll")                                                      \
        for (int g = 0; g < 4; ++g) {                                          \
            int base = (prow0 + g) * 18 + mcol;                                \
            bf8v af;                                                           \
            _Pragma("unroll")                                                  \
            for (int j = 0; j < 8; ++j) {                                      \
                __hip_bfloat16_raw r = (__hip_bfloat16_raw)flat[toff[j] + base];\
                af[j] = (short)r.x;                                            \
            }                                                                  \
            acc[PH][g] = __builtin_amdgcn_mfma_f32_16x16x32_bf16(af, wf,       \
                                                      acc[PH][g], 0, 0, 0);    \
        }                                                                      \
    }

template <int CITOT, int CIA>
__global__ __launch_bounds__(256)
void convt_mfma(const bf* __restrict__ inA, const bf* __restrict__ inB,
                const float* __restrict__ Wt, const float* __restrict__ Bias,
                bf* __restrict__ out,
                int N, int Hi, int Wi, int Cotot, int Ho, int Wo, int tilesX)
{
    constexpr int NCH = CITOT / 32;
    __shared__ bf sIn[32][17][18];                // 306 elems per ci
    __shared__ __align__(16) bf sWt[16][328];     // phase bases 0,40,112,184

    int tile = blockIdx.x;
    int J0 = (tile % tilesX) * 16, I0 = (tile / tilesX) * 16;
    int n = blockIdx.y;
    int cog0 = blockIdx.z * 16;
    int t = threadIdx.x;
    int lane = t & 63, wave = t >> 6;
    int q = lane >> 4, mcol = lane & 15;
    int prow0 = wave * 4;

    f4v acc[4][4];
    #pragma unroll
    for (int p = 0; p < 4; ++p)
        #pragma unroll
        for (int g = 0; g < 4; ++g) acc[p][g] = (f4v){0.f, 0.f, 0.f, 0.f};

    const bf* flat = (const bf*)sIn;

    for (int cb = 0; cb < NCH; ++cb) {
        if (cb) __syncthreads();                  // drain reads before restage
        for (int e = t; e < 32 * 306; e += 256) {
            int ci = e / 306, rem = e % 306;
            int py = rem / 18, px = rem % 18;
            int iy = I0 + py, ix = J0 + px;
            int gci = cb * 32 + ci;
            const bf* src = (gci < CIA)
                ? inA + (size_t)(n * CIA + gci) * Hi * Wi
                : inB + (size_t)(n * (CITOT - CIA) + gci - CIA) * Hi * Wi;
            sIn[ci][py][px] = (py < 17 && iy < Hi && px < 17 && ix < Wi)
                              ? src[(size_t)iy * Wi + ix] : f2bf(0.f);
        }
        for (int e = t; e < 16 * 288; e += 256) {
            int co = e / 288, rem = e % 288;
            int cic = rem / 9, t9 = rem % 9;
            int ky = t9 / 3, kx = t9 % 3;
            int ry = (ky == 1) ? 0 : 1;
            int rx = (kx == 1) ? 0 : 1;
            int ty = (ky == 1) ? 0 : (ky >> 1);
            int txi = (kx == 1) ? 0 : (kx >> 1);
            int ntx = 1 + rx;
            int ntaps = (1 + ry) * (1 + rx);
            int ph = ry * 2 + rx;
            const int base4[4] = {0, 40, 112, 184};
            int kl = cic * ntaps + ty * ntx + txi;
            sWt[co][base4[ph] + kl] =
                f2bf(Wt[(size_t)(cog0 + co) * CITOT * 9
                        + (size_t)(cb * 32 + cic) * 9 + t9]);
        }
        __syncthreads();

        CVT_PHASE(0,   0, 1, 0, 0)    // (ry0,rx0) 1 tap,  K=32
        CVT_PHASE(1,  40, 2, 1, 1)    // (ry0,rx1) 2 taps, K=64
        CVT_PHASE(2, 112, 2, 1, 0)    // (ry1,rx0) 2 taps, K=64
        CVT_PHASE(3, 184, 4, 2, 1)    // (ry1,rx1) 4 taps, K=128
    }

    float bs = Bias[cog0 + mcol];
    bf* dst = out + (size_t)(n * Cotot + cog0 + mcol) * Ho * Wo;
    #pragma unroll
    for (int ph = 0; ph < 4; ++ph) {
        const int ry = ph >> 1, rx = ph & 1;
        #pragma unroll
        for (int g = 0; g < 4; ++g) {
            int oy = 2 * (I0 + prow0 + g) + ry;
            #pragma unroll
            for (int jj = 0; jj < 4; ++jj) {
                int ox = 2 * (J0 + q * 4 + jj) + rx;
                dst[(size_t)oy * Wo + ox] = f2bf(fmaxf(acc[ph][g][jj] + bs, 0.f));
            }
        }
    }
}

// ===========================================================================
// NEW: MFMA Gram partials. sim = F(32 x K) * F^T done as 4096 K-chunks of 256.
// Block: stage [32][256] bf16 tile; wave w owns 16x16 quadrant (qr,qc);
// 8 MFMAs (K=32 each), A/B frags are contiguous ds_read_b128. Deterministic.
// ===========================================================================
__global__ __launch_bounds__(256)
void sim_partial(const bf* __restrict__ f, float* __restrict__ part, int KTOT)
{
    __shared__ __align__(16) bf tile[32][264];   // row stride 264 (528B, 16B-aligned)
    int c = blockIdx.x;
    int t = threadIdx.x;
    int k0 = c << 8;

    for (int e = t; e < 1024; e += 256) {        // 1024 uint4 = 32x256 bf16
        int row = e >> 5, col8 = (e & 31) * 8;
        uint4 v = *(const uint4*)&f[(size_t)row * KTOT + k0 + col8];
        *(uint4*)&tile[row][col8] = v;
    }
    __syncthreads();

    int lane = t & 63, wave = t >> 6;
    int q = lane >> 4, mcol = lane & 15;
    int qr = wave >> 1, qc = wave & 1;

    f4v acc = (f4v){0.f, 0.f, 0.f, 0.f};
    #pragma unroll
    for (int ks = 0; ks < 8; ++ks) {
        bf8v a = *(const bf8v*)&tile[qr * 16 + mcol][ks * 32 + q * 8];
        bf8v b = *(const bf8v*)&tile[qc * 16 + mcol][ks * 32 + q * 8];
        acc = __builtin_amdgcn_mfma_f32_16x16x32_bf16(a, b, acc, 0, 0, 0);
    }

    float* dst = part + (size_t)c * 1024;
    #pragma unroll
    for (int jj = 0; jj < 4; ++jj) {
        int i = qr * 16 + q * 4 + jj;            // D row = i
        int j = qc * 16 + mcol;                  // D col = j
        dst[i * 32 + j] = acc[jj];
    }
}

__global__ __launch_bounds__(256)
void sim_reduce(const float* __restrict__ part, float* __restrict__ sim, int nchunks)
{
    __shared__ float red[256];
    int pair = blockIdx.x;
    int t = threadIdx.x;
    float s = 0.f;
    for (int k = t; k < nchunks; k += 256)
        s += part[(size_t)k * 1024 + pair];
    red[t] = s;
    __syncthreads();
    #pragma unroll
    for (int off = 128; off > 0; off >>= 1) {
        if (t < off) red[t] += red[t + off];
        __syncthreads();
    }
    if (t == 0) sim[pair] = red[0];
}

// ===========================================================================
// Cosine sim + group mask + top-3 (strict >, lowest index wins ties).
// ===========================================================================
__global__ void topk_kernel(const float* __restrict__ sim, const int* __restrict__ prange,
                            int* __restrict__ idx, int N)
{
    int i = threadIdx.x;
    if (i >= N) return;
    float nm_i = fmaxf(sqrtf(sim[i * N + i]), 1e-8f);
    int p0 = prange[0], p1 = prange[1];
    int gi = (i >= p0) + (i >= p1);
    float vals[32];
    for (int j = 0; j < N; ++j) {
        int gj = (j >= p0) + (j >= p1);
        if (j == i || gj != gi) { vals[j] = -1e30f; continue; }
        float nm_j = fmaxf(sqrtf(sim[j * N + j]), 1e-8f);
        vals[j] = sim[i * N + j] / (nm_i * nm_j);
    }
    for (int k = 0; k < 3; ++k) {
        float best = -2e30f; int bj = 0;
        for (int j = 0; j < N; ++j)
            if (vals[j] > best) { best = vals[j]; bj = j; }
        idx[i * 3 + k] = bj;
        vals[bj] = -1e30f;
    }
}

// ===========================================================================
// Gather-mean: agg[n] = (ga[i0] + ga[i1] + ga[i2]) / 3.
// ===========================================================================
__global__ __launch_bounds__(256)
void gather_mean(const bf* __restrict__ ga, const int* __restrict__ idx,
                 bf* __restrict__ agg)
{
    int n = blockIdx.y;
    int v = blockIdx.x * 256 + threadIdx.x;
    int i0 = idx[n * 3 + 0], i1 = idx[n * 3 + 1], i2 = idx[n * 3 + 2];
    const size_t stride = (size_t)16 << 16;
    const uint4* p0 = (const uint4*)(ga + stride * i0) + v;
    const uint4* p1 = (const uint4*)(ga + stride * i1) + v;
    const uint4* p2 = (const uint4*)(ga + stride * i2) + v;
    uint4 a = *p0, b = *p1, c = *p2;
    uint4 r;
    unsigned* ap = (unsigned*)&a; unsigned* bp = (unsigned*)&b;
    unsigned* cp = (unsigned*)&c; unsigned* rp = (unsigned*)&r;
    #pragma unroll
    for (int w = 0; w < 4; ++w) {
        float fa0 = __bfloat162float((__hip_bfloat16_raw){(unsigned short)(ap[w] & 0xffff)});
        float fb0 = __bfloat162float((__hip_bfloat16_raw){(unsigned short)(bp[w] & 0xffff)});
        float fc0 = __bfloat162float((__hip_bfloat16_raw){(unsigned short)(cp[w] & 0xffff)});
        float fa1 = __bfloat162float((__hip_bfloat16_raw){(unsigned short)(ap[w] >> 16)});
        float fb1 = __bfloat162float((__hip_bfloat16_raw){(unsigned short)(bp[w] >> 16)});
        float fc1 = __bfloat162float((__hip_bfloat16_raw){(unsigned short)(cp[w] >> 16)});
        rp[w] = packbf((fa0 + fb0 + fc0) * (1.f / 3.f),
                       (fa1 + fb1 + fc1) * (1.f / 3.f));
    }
    *((uint4*)(agg + stride * n) + v) = r;
}

// ===========================================================================
// Light head: gnn (bf16) + d1 recompute + dense 32->2 + softmax.
// ===========================================================================
__global__ __launch_bounds__(256)
void head_tiled(const float* __restrict__ cts, const bf* __restrict__ gnn,
                const float* __restrict__ w_d1, const float* __restrict__ b_d1,
                const float* __restrict__ w_de, const float* __restrict__ b_de,
                float* __restrict__ out, int N)
{
    __shared__ float sCts[18][19];
    __shared__ float sWd1[144];
    __shared__ float sB1[16];
    __shared__ float sDe[64];

    int tile = blockIdx.x;
    int X0 = (tile & 15) * 16, Y0 = (tile >> 4) * 16;
    int n = blockIdx.y;
    int t = threadIdx.x, tx = t & 15, ty = t >> 4;

    for (int e = t; e < 18 * 18; e += 256) {
        int py = e / 18, px = e % 18;
        int iy = Y0 - 1 + py, ix = X0 - 1 + px;
        sCts[py][px] = ((unsigned)iy < 256u && (unsigned)ix < 256u)
                       ? cts[((size_t)n << 16) + (iy << 8) + ix] : 0.f;
    }
    if (t < 144) sWd1[t] = w_d1[t];
    else if (t < 160) sB1[t - 144] = b_d1[t - 144];
    else if (t >= 192 && t < 256) sDe[t - 192] = w_de[t - 192];
    __syncthreads();

    int pix = ((Y0 + ty) << 8) + X0 + tx;
    float l0 = b_de[0], l1 = b_de[1];

    #pragma unroll
    for (int c = 0; c < 16; ++c) {
        float v = bf2f(gnn[((size_t)(n * 16 + c) << 16) + pix]);
        l0 = fmaf(v, sDe[c * 2 + 0], l0);
        l1 = fmaf(v, sDe[c * 2 + 1], l1);
    }

    float ct[3][3];
    #pragma unroll
    for (int a = 0; a < 3; ++a)
        #pragma unroll
        for (int b = 0; b < 3; ++b)
            ct[a][b] = sCts[ty + a][tx + b];
    #pragma unroll
    for (int c = 0; c < 16; ++c) {
        float a1 = sB1[c];
        #pragma unroll
        for (int t9 = 0; t9 < 9; ++t9)
            a1 = fmaf(ct[t9 / 3][t9 % 3], sWd1[c * 9 + t9], a1);
        float v = fmaxf(a1, 0.f);
        l0 = fmaf(v, sDe[(16 + c) * 2 + 0], l0);
        l1 = fmaf(v, sDe[(16 + c) * 2 + 1], l1);
    }

    float m = fmaxf(l0, l1);
    float e0 = expf(l0 - m), e1 = expf(l1 - m);
    float inv = 1.f / (e0 + e1);
    size_t base = ((size_t)n * 2) << 16;
    out[base + pix] = e0 * inv;
    out[base + 65536 + pix] = e1 * inv;
}

// ===========================================================================

extern "C" void kernel_launch(void* const* d_in, const int* in_sizes, int n_in,
                              void* d_out, int out_size, void* d_ws, size_t ws_size,
                              hipStream_t stream)
{
    const float* cts  = (const float*)d_in[0];
    const int*   prng = (const int*)d_in[1];
    const float* w_d1 = (const float*)d_in[2];  const float* b_d1 = (const float*)d_in[3];
    const float* w_d2 = (const float*)d_in[4];  const float* b_d2 = (const float*)d_in[5];
    const float* w_d3 = (const float*)d_in[6];  const float* b_d3 = (const float*)d_in[7];
    const float* w_d4 = (const float*)d_in[8];  const float* b_d4 = (const float*)d_in[9];
    const float* w_u1 = (const float*)d_in[10]; const float* b_u1 = (const float*)d_in[11];
    const float* w_u2 = (const float*)d_in[12]; const float* b_u2 = (const float*)d_in[13];
    const float* w_u3 = (const float*)d_in[14]; const float* b_u3 = (const float*)d_in[15];
    const float* w_ga = (const float*)d_in[16]; const float* b_ga = (const float*)d_in[17];
    const float* w_gu = (const float*)d_in[18]; const float* b_gu = (const float*)d_in[19];
    const float* w_de = (const float*)d_in[20]; const float* b_de = (const float*)d_in[21];

    const int H = 256, Wd = 256;
    const int N = in_sizes[0] / (H * Wd);   // 32

    // ---- workspace layout (192 MiB total), lifetime reuse ----
    char* wsb = (char*)d_ws;
    bf* u3 = (bf*)(wsb);
    bf* R1 = (bf*)(wsb + 67108864);

    bf* d1 = R1;
    bf* d2 = (bf*)(wsb + 134217728);
    bf* d3 = (bf*)(wsb + 134217728 + 33554432);
    bf* d4 = (bf*)(wsb + 134217728 + 50331648);
    bf* u1 = R1;
    bf* u2 = (bf*)(wsb + 67108864 + 16777216);
    bf* ga = R1;
    bf* gnn = R1;
    bf* agg = (bf*)(wsb + 134217728);
    float* simp = (float*)(wsb + 134217728);
    float* sim  = (float*)(wsb + 134217728 + 16777216);
    int*   idx  = (int*)d_out + (out_size - 96);

    const int KTOT = 16 * H * Wd;
    const int NCH  = KTOT / 256;            // 4096 chunks

    // encoder
    conv32<float><<<dim3(64, N), 256, 0, stream>>>(cts, cts, 1, 1, w_d1, b_d1, d1, N);
    conv_tiled<bf, 2><<<dim3(64, N, 2), 256, 0, stream>>>(
        d1, (const bf*)nullptr, 16, 16, w_d2, b_d2, d2, N, 256, 256, 32, 128, 128, 8);
    conv_tiled<bf, 2><<<dim3(16, N, 4), 256, 0, stream>>>(
        d2, (const bf*)nullptr, 32, 32, w_d3, b_d3, d3, N, 128, 128, 64, 64, 64, 4);
    conv_tiled<bf, 2><<<dim3(4, N, 8), 256, 0, stream>>>(
        d3, (const bf*)nullptr, 64, 64, w_d4, b_d4, d4, N, 64, 64, 128, 32, 32, 2);
    // decoder (all transposed convs via MFMA)
    convt_mfma<128, 128><<<dim3(4, N, 4), 256, 0, stream>>>(
        d4, d4, w_u1, b_u1, u1, N, 32, 32, 64, 64, 64, 2);
    convt_mfma<128, 64><<<dim3(16, N, 2), 256, 0, stream>>>(
        u1, d3, w_u2, b_u2, u2, N, 64, 64, 32, 128, 128, 4);
    convt_mfma<64, 32><<<dim3(64, N, 1), 256, 0, stream>>>(
        u2, d2, w_u3, b_u3, u3, N, 128, 128, 16, 256, 256, 8);
    // cosine similarity + top-3 (Gram via MFMA)
    sim_partial<<<NCH, 256, 0, stream>>>(u3, simp, KTOT);
    sim_reduce<<<dim3(N * N), 256, 0, stream>>>(simp, sim, NCH);
    topk_kernel<<<1, 64, 0, stream>>>(sim, prng, idx, N);
    // per-slice gnn-neighbor conv (MFMA), then gather-mean
    conv_mfma<16, 160><<<dim3(256, N), 256, 0, stream>>>(
        u3, u3, 16, w_ga, b_ga, ga, N);
    gather_mean<<<dim3(512, N), 256, 0, stream>>>(ga, idx, agg);
    // gnn conv (MFMA, 32ch from u3|agg) then light head
    conv_mfma<32, 288><<<dim3(256, N), 256, 0, stream>>>(
        u3, agg, 16, w_gu, b_gu, gnn, N);
    head_tiled<<<dim3(256, N), 256, 0, stream>>>(
        cts, gnn, w_d1, b_d1, w_de, b_de, (float*)d_out, N);
}